// Round 8
// baseline (3467.949 us; speedup 1.0000x reference)
//
#include <hip/hip_runtime.h>
#include <hip/hip_bf16.h>
#include <cstdint>
#include <cstddef>

using bf16 = __hip_bfloat16;

typedef __attribute__((ext_vector_type(8))) short s8vec;    // 8 x bf16 MFMA frag
typedef __attribute__((ext_vector_type(4))) float f4vec;    // 4 x fp32 accumulator

#define SD 4096
#define TD 64
#define ID 64
#define EHD 128
#define ED 256
#define HD 512
#define GD 2048
#define OD 128
#define F1D 256
#define F2D 64

__device__ __forceinline__ float sigmf(float x) { return 1.0f / (1.0f + __expf(-x)); }
__device__ __forceinline__ float tanh_fast(float x) { return 1.0f - 2.0f / (__expf(2.0f * x) + 1.0f); }

__device__ __forceinline__ void async16(const bf16* g, void* lds) {
    __builtin_amdgcn_global_load_lds(
        (const __attribute__((address_space(1))) void*)g,
        (__attribute__((address_space(3))) void*)lds, 16, 0, 0);
}

__device__ __forceinline__ float bfbits2f(unsigned short u) {
    union { unsigned int i; float f; } v; v.i = (unsigned int)u << 16; return v.f;
}

__device__ __forceinline__ uint4 bfmax8(uint4 a, uint4 b) {
    const unsigned short* pa = (const unsigned short*)&a;
    const unsigned short* pb = (const unsigned short*)&b;
    uint4 r; unsigned short* pr = (unsigned short*)&r;
#pragma unroll
    for (int e = 0; e < 8; ++e)
        pr[e] = (bfbits2f(pa[e]) > bfbits2f(pb[e])) ? pa[e] : pb[e];
    return r;
}

// Fragment-ordered tile layout (128x128 bf16 tile = 16384 elems = 2048 slots
// of 16B). Slot for wave-quadrant wq, ks-step, block mi, lane:
//   slot = ((wq*4+ks)*4+mi)*64 + lane,  element  = slot*8 + e
// Fragment element: row = wq*64+mi*16+(lane&15), k = ks*32+(lane>>4)*8+e.
// Readers do ds_read_b128 at consecutive-lane addresses -> conflict-free;
// DMA staging source is linear -> perfectly coalesced.
__device__ __forceinline__ int frag_off(int row, int k) {
    int wq = row >> 6, mi = (row >> 4) & 3, lm = row & 15;
    int ks = (k >> 5) & 3, lq = (k >> 3) & 3, e8 = k & 7;
    return ((((wq * 4 + ks) * 4 + mi) * 64 + lq * 16 + lm) << 3) + e8;
}

// ---------------------------------------------------------------------------
// Fused per-step LSTM kernel. Grid (32,16), 256 thr, 128x128 tile, BK=128.
// A = concat(x_t[frag-ordered], maxpool3(hR)[staged manually]), B = WpackF
// (fragment-ordered, gate-permuted). Epilogue does the cell update.
// ---------------------------------------------------------------------------
__global__ __launch_bounds__(256, 2)
void lstm_fused(const bf16* __restrict__ xF,     // frag tiles for this t: [(mt*2+ki)][16384]
                const bf16* __restrict__ hR,     // prev un-pooled h [SD][HD]
                bf16* __restrict__ hW,           // this step un-pooled h
                const bf16* __restrict__ WpackF, // frag tiles [(nt*6+ki)][16384]
                const float* __restrict__ biasg,
                const float* __restrict__ c_in,
                float* __restrict__ c_out)
{
    __shared__ __align__(16) bf16 As[128 * 128];   // 32 KB
    __shared__ __align__(16) bf16 Bs[128 * 128];   // 32 KB

    const int tid = threadIdx.x;
    const int lane = tid & 63;
    const int w = tid >> 6;
    const int wm = w & 1, wn = w >> 1;
    const int mt = blockIdx.x, nt = blockIdx.y;
    const int m0 = mt * 128, n0 = nt * 128;
    const int lm = lane & 15, lq = lane >> 4;

    f4vec acc[4][4];
#pragma unroll
    for (int i = 0; i < 4; ++i)
#pragma unroll
        for (int jj = 0; jj < 4; ++jj) acc[i][jj] = (f4vec){0.f, 0.f, 0.f, 0.f};

    for (int ki = 0; ki < 6; ++ki) {
        if (ki < 2) {
            // x-part: frag-ordered, linear DMA
            const bf16* src = xF + ((size_t)(mt * 2 + ki) << 14);
#pragma unroll
            for (int it = 0; it < 8; ++it) {
                uint32_t off = (uint32_t)(it * 256 + (tid & ~63)) * 16u;
                async16(src + (size_t)(it * 256 + tid) * 8, (char*)As + off);
            }
        } else {
            // h-part: manual staging with fused 3-tap spatial maxpool,
            // written into fragment order (linear per-wave -> conflict-free)
            const int kkj = (ki - 2) * 128;
#pragma unroll
            for (int it = 0; it < 8; ++it) {
                int s = it * 256 + tid;
                int sl = s & 63;
                int mi = (s >> 6) & 3, ks = (s >> 8) & 3, wq = s >> 10;
                int row = m0 + wq * 64 + mi * 16 + (sl & 15);
                int jj = kkj + ks * 32 + (sl >> 4) * 8;
                const bf16* base = hR + (size_t)row * HD + jj;
                uint4 v = *(const uint4*)base;
                if (row > 0)      v = bfmax8(v, *(const uint4*)(base - HD));
                if (row < SD - 1) v = bfmax8(v, *(const uint4*)(base + HD));
                *(uint4*)(As + s * 8) = v;
            }
        }
        {
            const bf16* src = WpackF + ((size_t)(nt * 6 + ki) << 14);
#pragma unroll
            for (int it = 0; it < 8; ++it) {
                uint32_t off = (uint32_t)(it * 256 + (tid & ~63)) * 16u;
                async16(src + (size_t)(it * 256 + tid) * 8, (char*)Bs + off);
            }
        }
        __syncthreads();
#pragma unroll
        for (int ks = 0; ks < 4; ++ks) {
            s8vec af[4], bfr[4];
#pragma unroll
            for (int mi = 0; mi < 4; ++mi)
                af[mi] = *(const s8vec*)(As + ((wm * 4 + ks) * 4 + mi) * 512 + lane * 8);
#pragma unroll
            for (int ni = 0; ni < 4; ++ni)
                bfr[ni] = *(const s8vec*)(Bs + ((wn * 4 + ks) * 4 + ni) * 512 + lane * 8);
#pragma unroll
            for (int mi = 0; mi < 4; ++mi)
#pragma unroll
                for (int ni = 0; ni < 4; ++ni)
                    acc[mi][ni] = __builtin_amdgcn_mfma_f32_16x16x32_bf16(af[mi], bfr[ni], acc[mi][ni], 0, 0, 0);
        }
        __syncthreads();
    }

    // epilogue: 4 ni-blocks = 4 gates of hidden unit j
    const int j = (n0 >> 2) + wn * 16 + lm;
    const float bi = biasg[n0 + wn * 64 + lm];
    const float bff = biasg[n0 + wn * 64 + 16 + lm];
    const float bg = biasg[n0 + wn * 64 + 32 + lm];
    const float bo = biasg[n0 + wn * 64 + 48 + lm];
#pragma unroll
    for (int mi = 0; mi < 4; ++mi) {
#pragma unroll
        for (int r = 0; r < 4; ++r) {
            const int row = m0 + wm * 64 + mi * 16 + lq * 4 + r;
            float gi = acc[mi][0][r] + bi;
            float gf = acc[mi][1][r] + bff;
            float gg = acc[mi][2][r] + bg;
            float go = acc[mi][3][r] + bo;
            float cn = sigmf(gf) * c_in[(size_t)row * HD + j] + sigmf(gi) * tanh_fast(gg);
            c_out[(size_t)row * HD + j] = cn;
            hW[(size_t)row * HD + j] = __float2bfloat16(sigmf(go) * tanh_fast(cn));
        }
    }
}

// ---------------------------------------------------------------------------
// Generic NT GEMM (m97 structure), 128x128 tile: embed + head.
// MODE_SCATTER / MODE_FRAG write fragment-ordered x2 (time-major / single-t).
// ---------------------------------------------------------------------------
constexpr int MODE_BF16 = 0;
constexpr int MODE_SCATTER = 2;
constexpr int MODE_FRAG = 3;

template <int MODE>
__global__ __launch_bounds__(256, 2)
void gemm_kernel(const bf16* __restrict__ A1, int lda1,
                 const bf16* __restrict__ B, int ldb,
                 const float* __restrict__ bias,
                 const float* __restrict__ scale,
                 int relu, void* __restrict__ Cp, int ldc,
                 int K, int ncols)
{
    __shared__ __align__(16) bf16 As[128 * 64];
    __shared__ __align__(16) bf16 Bs[128 * 64];

    const int tid = threadIdx.x;
    const int lane = tid & 63;
    const int w = tid >> 6;
    const int wm = w & 1, wn = w >> 1;
    const int m0 = blockIdx.x * 128, n0 = blockIdx.y * 128;
    const int lm = lane & 15, lq = lane >> 4;

    f4vec acc[4][4];
#pragma unroll
    for (int i = 0; i < 4; ++i)
#pragma unroll
        for (int jj = 0; jj < 4; ++jj) acc[i][jj] = (f4vec){0.f, 0.f, 0.f, 0.f};

    for (int kc = 0; kc < K; kc += 64) {
#pragma unroll
        for (int it = 0; it < 4; ++it) {
            int flat = it * 256 + tid;
            int row = flat >> 3, colu = flat & 7;
            const bf16* ga = A1 + (size_t)(m0 + row) * lda1 + kc + colu * 8;
            const bf16* gb = B + (size_t)(n0 + row) * ldb + kc + colu * 8;
            uint32_t off = (uint32_t)(it * 256 + (tid & ~63)) * 16u;
            async16(ga, (char*)As + off);
            async16(gb, (char*)Bs + off);
        }
        __syncthreads();
#pragma unroll
        for (int ks = 0; ks < 64; ks += 32) {
            s8vec af[4], bfr[4];
#pragma unroll
            for (int mi = 0; mi < 4; ++mi)
                af[mi] = *(const s8vec*)(As + (wm * 64 + mi * 16 + lm) * 64 + ks + lq * 8);
#pragma unroll
            for (int ni = 0; ni < 4; ++ni)
                bfr[ni] = *(const s8vec*)(Bs + (wn * 64 + ni * 16 + lm) * 64 + ks + lq * 8);
#pragma unroll
            for (int mi = 0; mi < 4; ++mi)
#pragma unroll
                for (int ni = 0; ni < 4; ++ni)
                    acc[mi][ni] = __builtin_amdgcn_mfma_f32_16x16x32_bf16(af[mi], bfr[ni], acc[mi][ni], 0, 0, 0);
        }
        __syncthreads();
    }

    const float sc = scale ? scale[0] : 1.0f;
#pragma unroll
    for (int mi = 0; mi < 4; ++mi) {
#pragma unroll
        for (int ni = 0; ni < 4; ++ni) {
            const int gcol = n0 + wn * 64 + ni * 16 + lm;
            const float bv = bias[gcol];
#pragma unroll
            for (int r = 0; r < 4; ++r) {
                const int grow = m0 + wm * 64 + mi * 16 + lq * 4 + r;
                float v = acc[mi][ni][r] * sc + bv;
                if (relu) v = fmaxf(v, 0.f);
                if constexpr (MODE == MODE_BF16) {
                    if (gcol < ncols)
                        ((bf16*)Cp)[(size_t)grow * ldc + gcol] = __float2bfloat16(v);
                } else if constexpr (MODE == MODE_SCATTER) {
                    // rows are s*64+t over [S*T]; dest frag-ordered [t][mt*2+ki][...]
                    int t = grow & 63, s = grow >> 6;
                    size_t addr = (size_t)t * (SD * ED)
                                + (size_t)((((s >> 7) * 2 + (gcol >> 7)) << 14)
                                           + frag_off(s & 127, gcol & 127));
                    ((bf16*)Cp)[addr] = __float2bfloat16(v);
                } else {  // MODE_FRAG: single-t, rows are s
                    size_t addr = (size_t)((((grow >> 7) * 2 + (gcol >> 7)) << 14)
                                           + frag_off(grow & 127, gcol & 127));
                    ((bf16*)Cp)[addr] = __float2bfloat16(v);
                }
            }
        }
    }
}

// ---------------------------------------------------------------------------
// Prep: WpackF fragment-ordered + gate-permuted; biasg permuted; weight cvts.
// ---------------------------------------------------------------------------
__global__ void prep_kernel(const float* __restrict__ Wih, const float* __restrict__ Whh,
                            const float* __restrict__ bih, const float* __restrict__ bhh,
                            const float* __restrict__ We1, const float* __restrict__ We2,
                            const float* __restrict__ Wout, const float* __restrict__ Wf1,
                            const float* __restrict__ Wf2, const float* __restrict__ bf2,
                            bf16* __restrict__ WpackF, float* __restrict__ biasg,
                            bf16* __restrict__ We1b, bf16* __restrict__ We2b,
                            bf16* __restrict__ Woutb, bf16* __restrict__ Wf1b,
                            bf16* __restrict__ Wf2p, float* __restrict__ bf2f)
{
    int idx = blockIdx.x * 256 + threadIdx.x;
    const int S0 = GD * (ED + HD);
    if (idx < S0) {
        int tile = idx >> 14;            // nt*6 + ki
        int within = idx & 16383;
        int slot = within >> 3, e8 = within & 7;
        int nt = tile / 6, ki = tile - nt * 6;
        int lanev = slot & 63, lmv = lanev & 15, lqv = lanev >> 4;
        int ni = (slot >> 6) & 3, ks = (slot >> 8) & 3, wnv = slot >> 10;
        int j = nt * 32 + wnv * 16 + lmv;
        int orig = ni * HD + j;          // ni = gate
        int kg = ki * 128 + ks * 32 + lqv * 8 + e8;
        float v = (kg < ED) ? Wih[(size_t)orig * ED + kg]
                            : Whh[(size_t)orig * HD + (kg - ED)];
        WpackF[idx] = __float2bfloat16(v);
        return;
    }
    idx -= S0;
    if (idx < GD) {
        int p = idx, q = p & 127;
        int jv = (p >> 7) * 32 + ((q >> 6) << 4) + (q & 15);
        int gate = (q >> 4) & 3;
        int orig = gate * HD + jv;
        biasg[p] = bih[orig] + bhh[orig];
        return;
    }
    idx -= GD;
    if (idx < EHD * ID) { We1b[idx] = __float2bfloat16(We1[idx]); return; }
    idx -= EHD * ID;
    if (idx < ED * EHD) { We2b[idx] = __float2bfloat16(We2[idx]); return; }
    idx -= ED * EHD;
    if (idx < OD * HD) { Woutb[idx] = __float2bfloat16(Wout[idx]); return; }
    idx -= OD * HD;
    if (idx < F1D * OD) { Wf1b[idx] = __float2bfloat16(Wf1[idx]); return; }
    idx -= F1D * OD;
    if (idx < 128 * F1D) {
        int nrow = idx >> 8;
        Wf2p[idx] = (nrow < F2D) ? __float2bfloat16(Wf2[idx]) : __float2bfloat16(0.f);
        return;
    }
    idx -= 128 * F1D;
    if (idx < 128) { bf2f[idx] = (idx < F2D) ? bf2[idx] : 0.f; return; }
}

__global__ void cvt_input_kernel(const float* __restrict__ src, bf16* __restrict__ dst)
{
    int i = (blockIdx.x * 256 + threadIdx.x) * 8;
    float4 a = *(const float4*)(src + i);
    float4 b = *(const float4*)(src + i + 4);
    bf16 o[8] = { __float2bfloat16(a.x), __float2bfloat16(a.y),
                  __float2bfloat16(a.z), __float2bfloat16(a.w),
                  __float2bfloat16(b.x), __float2bfloat16(b.y),
                  __float2bfloat16(b.z), __float2bfloat16(b.w) };
    *(uint4*)(dst + i) = *(const uint4*)o;
}

__global__ void lane_kernel(const float* __restrict__ lane, const float* __restrict__ Wlg1,
                            const float* __restrict__ blg1, const float* __restrict__ Wlg2,
                            const float* __restrict__ blg2, float* __restrict__ laneC)
{
    if (threadIdx.x != 0) return;
    const float l = lane[0];
    float acc = blg2[0];
    for (int k = 0; k < 32; ++k)
        acc += fmaxf(l * Wlg1[k] + blg1[k], 0.f) * Wlg2[k];
    float v = 1.f / (1.f + __expf(-acc));
    laneC[0] = v;
    laneC[1] = 1.f / v;
}

__global__ void zero_kernel(float* __restrict__ c0, bf16* __restrict__ hp)
{
    int idx = blockIdx.x * 256 + threadIdx.x;
    if (idx < SD * HD) {
        c0[idx] = 0.f;
        hp[idx] = __float2bfloat16(0.f);
    }
}

__global__ void maxpool_kernel(const bf16* __restrict__ hp, bf16* __restrict__ hout)
{
    int base = (blockIdx.x * 256 + threadIdx.x) * 8;
    int s = base >> 9;
    uint4 res = *(const uint4*)(hp + base);
    if (s > 0)      res = bfmax8(res, *(const uint4*)(hp + base - HD));
    if (s < SD - 1) res = bfmax8(res, *(const uint4*)(hp + base + HD));
    *(uint4*)(hout + base) = res;
}

__global__ void f3_kernel(const bf16* __restrict__ xf2, const float* __restrict__ Wf3,
                          const float* __restrict__ bf3, const float* __restrict__ laneC,
                          float* __restrict__ out)
{
    int s = blockIdx.x * 256 + threadIdx.x;
    if (s >= SD) return;
    float acc = bf3[0];
#pragma unroll
    for (int k = 0; k < F2D; ++k)
        acc += __bfloat162float(xf2[(size_t)s * F2D + k]) * Wf3[k];
    out[s] = acc * laneC[1];
}

__global__ void finalize_kernel(const bf16* __restrict__ h, const float* __restrict__ c,
                                float* __restrict__ out)
{
    int idx = (blockIdx.x * 256 + threadIdx.x) * 4;
    if (idx >= SD * HD) return;
    uint2 hv4 = *(const uint2*)(h + idx);
    const unsigned short* hu = (const unsigned short*)&hv4;
    float4 hf = { bfbits2f(hu[0]), bfbits2f(hu[1]), bfbits2f(hu[2]), bfbits2f(hu[3]) };
    *(float4*)(out + SD + idx) = hf;
    *(float4*)(out + SD + SD * HD + idx) = *(const float4*)(c + idx);
}

// ---------------------------------------------------------------------------
extern "C" void kernel_launch(void* const* d_in, const int* in_sizes, int n_in,
                              void* d_out, int out_size, void* d_ws, size_t ws_size,
                              hipStream_t stream)
{
    (void)in_sizes; (void)n_in; (void)out_size;
    const float* inputDataF = (const float*)d_in[0];
    const float* lane = (const float*)d_in[1];
    const float* Wlg1 = (const float*)d_in[2];
    const float* blg1 = (const float*)d_in[3];
    const float* Wlg2 = (const float*)d_in[4];
    const float* blg2 = (const float*)d_in[5];
    const float* We1 = (const float*)d_in[6];
    const float* be1 = (const float*)d_in[7];
    const float* We2 = (const float*)d_in[8];
    const float* be2 = (const float*)d_in[9];
    const float* Wih = (const float*)d_in[10];
    const float* bih = (const float*)d_in[11];
    const float* Whh = (const float*)d_in[12];
    const float* bhh = (const float*)d_in[13];
    const float* Wout = (const float*)d_in[14];
    const float* bout = (const float*)d_in[15];
    const float* Wf1 = (const float*)d_in[16];
    const float* bf1 = (const float*)d_in[17];
    const float* Wf2 = (const float*)d_in[18];
    const float* bf2 = (const float*)d_in[19];
    const float* Wf3 = (const float*)d_in[20];
    const float* bf3 = (const float*)d_in[21];
    float* out = (float*)d_out;

    char* wp = (char*)d_ws;
    auto carve = [&](size_t bytes) { char* p = wp; wp += (bytes + 255) & ~(size_t)255; return p; };

    bf16* inb   = (bf16*)carve((size_t)SD * TD * ID * 2);
    float* laneCbuf = (float*)carve(2 * sizeof(float));
    float* cbuf0 = (float*)carve((size_t)SD * HD * 4);
    float* cbuf1 = (float*)carve((size_t)SD * HD * 4);
    bf16* hbuf  = (bf16*)carve((size_t)SD * HD * 2);
    bf16* hpA   = (bf16*)carve((size_t)SD * HD * 2);
    bf16* hpB   = (bf16*)carve((size_t)SD * HD * 2);
    bf16* WpackF = (bf16*)carve((size_t)GD * (ED + HD) * 2);
    float* biasg = (float*)carve(GD * 4);
    float* bf2f = (float*)carve(128 * 4);
    bf16* We1b  = (bf16*)carve((size_t)EHD * ID * 2);
    bf16* We2b  = (bf16*)carve((size_t)ED * EHD * 2);
    bf16* Woutb = (bf16*)carve((size_t)OD * HD * 2);
    bf16* Wf1b  = (bf16*)carve((size_t)F1D * OD * 2);
    bf16* Wf2p  = (bf16*)carve((size_t)128 * F1D * 2);
    bf16* out_o = (bf16*)carve((size_t)SD * OD * 2);
    bf16* xf1   = (bf16*)carve((size_t)SD * F1D * 2);
    bf16* xf2   = (bf16*)carve((size_t)SD * F2D * 2);

    const size_t SZ_X1 = (size_t)SD * TD * EHD * 2;
    const size_t SZ_X2 = (size_t)SD * TD * ED * 2;
    const size_t used = (size_t)(wp - (char*)d_ws);
    const size_t remain = (ws_size > used) ? (ws_size - used) : 0;
    const bool persist = remain >= (SZ_X1 + SZ_X2 + 4096);

    bf16* x1 = nullptr; bf16* x2F = nullptr;
    bf16* x1t = nullptr; bf16* x2tF = nullptr;
    if (persist) {
        x1 = (bf16*)carve(SZ_X1);
        x2F = (bf16*)carve(SZ_X2);
    } else {
        x1t = (bf16*)carve((size_t)SD * EHD * 2);
        x2tF = (bf16*)carve((size_t)SD * ED * 2);
    }

    const int PREP_N = GD * (ED + HD) + GD + EHD * ID + ED * EHD + OD * HD
                     + F1D * OD + 128 * F1D + 128;

    cvt_input_kernel<<<SD * TD * ID / (256 * 8), 256, 0, stream>>>(inputDataF, inb);
    prep_kernel<<<(PREP_N + 255) / 256, 256, 0, stream>>>(
        Wih, Whh, bih, bhh, We1, We2, Wout, Wf1, Wf2, bf2,
        WpackF, biasg, We1b, We2b, Woutb, Wf1b, Wf2p, bf2f);
    lane_kernel<<<1, 64, 0, stream>>>(lane, Wlg1, blg1, Wlg2, blg2, laneCbuf);
    zero_kernel<<<SD * HD / 256, 256, 0, stream>>>(cbuf0, hpB);

    if (persist) {
        gemm_kernel<MODE_BF16><<<dim3(SD * TD / 128, 1), 256, 0, stream>>>(
            inb, ID, We1b, ID, be1, laneCbuf, 1, x1, EHD, ID, EHD);
        gemm_kernel<MODE_SCATTER><<<dim3(SD * TD / 128, ED / 128), 256, 0, stream>>>(
            x1, EHD, We2b, EHD, be2, nullptr, 1, x2F, ED, EHD, ED);
    }

    // LSTM: 64 per-step fused dispatches (GEMM + cell update + pool-on-read)
    for (int t = 0; t < TD; ++t) {
        const float* c_in = (t & 1) ? cbuf1 : cbuf0;
        float* c_out = (t & 1) ? cbuf0 : cbuf1;
        const bf16* hR = (t & 1) ? hpA : hpB;
        bf16* hW = (t & 1) ? hpB : hpA;
        const bf16* xF;
        if (persist) {
            xF = x2F + (size_t)t * SD * ED;
        } else {
            gemm_kernel<MODE_BF16><<<dim3(SD / 128, 1), 256, 0, stream>>>(
                inb + (size_t)t * ID, TD * ID, We1b, ID, be1, laneCbuf, 1,
                x1t, EHD, ID, EHD);
            gemm_kernel<MODE_FRAG><<<dim3(SD / 128, ED / 128), 256, 0, stream>>>(
                x1t, EHD, We2b, EHD, be2, nullptr, 1, x2tF, ED, EHD, ED);
            xF = x2tF;
        }
        lstm_fused<<<dim3(SD / 128, GD / 128), 256, 0, stream>>>(
            xF, hR, hW, WpackF, biasg, c_in, c_out);
    }
    // t=63: hW = hpB holds final un-pooled h; c_out = cbuf0 holds final c
    maxpool_kernel<<<SD * HD / (256 * 8), 256, 0, stream>>>(hpB, hbuf);

    // Output head
    gemm_kernel<MODE_BF16><<<dim3(SD / 128, 1), 256, 0, stream>>>(
        hbuf, HD, Woutb, HD, bout, nullptr, 0, out_o, OD, HD, OD);
    gemm_kernel<MODE_BF16><<<dim3(SD / 128, F1D / 128), 256, 0, stream>>>(
        out_o, OD, Wf1b, OD, bf1, nullptr, 1, xf1, F1D, OD, F1D);
    gemm_kernel<MODE_BF16><<<dim3(SD / 128, 1), 256, 0, stream>>>(
        xf1, F1D, Wf2p, F1D, bf2f, nullptr, 1, xf2, F2D, F1D, F2D);
    f3_kernel<<<SD / 256, 256, 0, stream>>>(xf2, Wf3, bf3, laneCbuf, out);
    finalize_kernel<<<SD * HD / (256 * 4), 256, 0, stream>>>(hbuf, cbuf0, out);
}

// Round 9
// 2696.907 us; speedup vs baseline: 1.2859x; 1.2859x over previous
//
#include <hip/hip_runtime.h>
#include <hip/hip_bf16.h>
#include <cstdint>
#include <cstddef>

using bf16 = __hip_bfloat16;

typedef __attribute__((ext_vector_type(8))) short s8vec;    // 8 x bf16 MFMA frag
typedef __attribute__((ext_vector_type(4))) float f4vec;    // 4 x fp32 accumulator

#define SD 4096
#define TD 64
#define ID 64
#define EHD 128
#define ED 256
#define HD 512
#define GD 2048
#define OD 128
#define F1D 256
#define F2D 64

__device__ __forceinline__ float sigmf(float x) { return 1.0f / (1.0f + __expf(-x)); }
__device__ __forceinline__ float tanh_fast(float x) { return 1.0f - 2.0f / (__expf(2.0f * x) + 1.0f); }

__device__ __forceinline__ void async16(const bf16* g, void* lds) {
    __builtin_amdgcn_global_load_lds(
        (const __attribute__((address_space(1))) void*)g,
        (__attribute__((address_space(3))) void*)lds, 16, 0, 0);
}

__device__ __forceinline__ float bfbits2f(unsigned short u) {
    union { unsigned int i; float f; } v; v.i = (unsigned int)u << 16; return v.f;
}

__device__ __forceinline__ uint4 bfmax8(uint4 a, uint4 b) {
    const unsigned short* pa = (const unsigned short*)&a;
    const unsigned short* pb = (const unsigned short*)&b;
    uint4 r; unsigned short* pr = (unsigned short*)&r;
#pragma unroll
    for (int e = 0; e < 8; ++e)
        pr[e] = (bfbits2f(pa[e]) > bfbits2f(pb[e])) ? pa[e] : pb[e];
    return r;
}

// Fragment tile: 128 rows x 64 k = 8192 bf16 = 1024 slots of 8 elems (16B).
// slot = ((wq*2+ks)*4+blk)*64 + lq*16 + lm ; row = wq*64+blk*16+lm ;
// k = ks*32+lq*8+e8.  Wave reads ds_read_b128 at base+lane*16 -> conflict-free.
__device__ __forceinline__ int frag_slot(int row, int k) {
    int wq = row >> 6, blk = (row >> 4) & 3, lm = row & 15;
    int ks = (k >> 5) & 1, lq = (k >> 3) & 3;
    return ((wq * 2 + ks) * 4 + blk) * 64 + lq * 16 + lm;
}

// ---------------------------------------------------------------------------
// Per-step LSTM gates GEMM (R4 structure, BK=64, 128x128 tile, grid (32,16)).
// A: ki<4 -> x_t natural rows (R4 staging+reads, conflicted but only 4/12);
//    ki>=4 -> hF fragment tiles (linear DMA, conflict-free reads).
// B: WpackF fragment tiles (linear DMA, conflict-free reads).
// Epilogue: 4 ni-blocks = 4 gates of j; cell update; natural c/hpre writes.
// ---------------------------------------------------------------------------
__global__ __launch_bounds__(256, 2)
void lstm_gemm2(const bf16* __restrict__ xt,      // [SD][ED] natural
                const bf16* __restrict__ hF,      // frag tiles [mt*8+kh][8192]
                const bf16* __restrict__ WpackF,  // frag tiles [nt*12+ki][8192]
                const float* __restrict__ biasg,
                const float* __restrict__ c_in, float* __restrict__ c_out,
                bf16* __restrict__ h_pre)         // [SD][HD] natural
{
    __shared__ __align__(16) bf16 As[128 * 64];
    __shared__ __align__(16) bf16 Bs[128 * 64];

    const int tid = threadIdx.x;
    const int lane = tid & 63;
    const int w = tid >> 6;
    const int wm = w & 1, wn = w >> 1;
    const int mt = blockIdx.x, nt = blockIdx.y;
    const int m0 = mt * 128, n0 = nt * 128;
    const int lm = lane & 15, lq = lane >> 4;

    f4vec acc[4][4];
#pragma unroll
    for (int i = 0; i < 4; ++i)
#pragma unroll
        for (int jj = 0; jj < 4; ++jj) acc[i][jj] = (f4vec){0.f, 0.f, 0.f, 0.f};

    for (int ki = 0; ki < 12; ++ki) {
        if (ki < 4) {
            // x-part: natural row-major staging (R4)
#pragma unroll
            for (int it = 0; it < 4; ++it) {
                int flat = it * 256 + tid;
                int row = flat >> 3, colu = flat & 7;
                const bf16* ga = xt + (size_t)(m0 + row) * ED + ki * 64 + colu * 8;
                uint32_t off = (uint32_t)(it * 256 + (tid & ~63)) * 16u;
                async16(ga, (char*)As + off);
            }
        } else {
            // h-part: fragment tile, linear DMA
            const bf16* src = hF + ((size_t)(mt * 8 + (ki - 4)) << 13);
#pragma unroll
            for (int it = 0; it < 4; ++it) {
                uint32_t off = (uint32_t)(it * 256 + (tid & ~63)) * 16u;
                async16(src + (size_t)(it * 256 + tid) * 8, (char*)As + off);
            }
        }
        {
            const bf16* src = WpackF + ((size_t)(nt * 12 + ki) << 13);
#pragma unroll
            for (int it = 0; it < 4; ++it) {
                uint32_t off = (uint32_t)(it * 256 + (tid & ~63)) * 16u;
                async16(src + (size_t)(it * 256 + tid) * 8, (char*)Bs + off);
            }
        }
        __syncthreads();
#pragma unroll
        for (int ksi = 0; ksi < 2; ++ksi) {
            s8vec af[4], bfr[4];
            if (ki < 4) {
#pragma unroll
                for (int mi = 0; mi < 4; ++mi)
                    af[mi] = *(const s8vec*)(As + (wm * 64 + mi * 16 + lm) * 64 + ksi * 32 + lq * 8);
            } else {
#pragma unroll
                for (int mi = 0; mi < 4; ++mi)
                    af[mi] = *(const s8vec*)(As + (((wm * 2 + ksi) * 4 + mi) << 9) + lane * 8);
            }
#pragma unroll
            for (int ni = 0; ni < 4; ++ni)
                bfr[ni] = *(const s8vec*)(Bs + (((wn * 2 + ksi) * 4 + ni) << 9) + lane * 8);
#pragma unroll
            for (int mi = 0; mi < 4; ++mi)
#pragma unroll
                for (int ni = 0; ni < 4; ++ni)
                    acc[mi][ni] = __builtin_amdgcn_mfma_f32_16x16x32_bf16(af[mi], bfr[ni], acc[mi][ni], 0, 0, 0);
        }
        __syncthreads();
    }

    const int j = (n0 >> 2) + wn * 16 + lm;
    const float bi = biasg[n0 + wn * 64 + lm];
    const float bff = biasg[n0 + wn * 64 + 16 + lm];
    const float bg = biasg[n0 + wn * 64 + 32 + lm];
    const float bo = biasg[n0 + wn * 64 + 48 + lm];
#pragma unroll
    for (int mi = 0; mi < 4; ++mi) {
#pragma unroll
        for (int r = 0; r < 4; ++r) {
            const int row = m0 + wm * 64 + mi * 16 + lq * 4 + r;
            float gi = acc[mi][0][r] + bi;
            float gf = acc[mi][1][r] + bff;
            float gg = acc[mi][2][r] + bg;
            float go = acc[mi][3][r] + bo;
            float cn = sigmf(gf) * c_in[(size_t)row * HD + j] + sigmf(gi) * tanh_fast(gg);
            c_out[(size_t)row * HD + j] = cn;
            h_pre[(size_t)row * HD + j] = __float2bfloat16(sigmf(go) * tanh_fast(cn));
        }
    }
}

// ---------------------------------------------------------------------------
// Per-step pool: hF[frag] = maxpool3(hpre). 8 elems/thread (one 16B chunk ->
// one frag slot; j 8-aligned => all 8 elems share a slot).
// ---------------------------------------------------------------------------
__global__ void pool_frag_kernel(const bf16* __restrict__ hp, bf16* __restrict__ hF)
{
    int base = (blockIdx.x * 256 + threadIdx.x) * 8;   // < SD*HD
    int s = base >> 9, j = base & 511;
    uint4 res = *(const uint4*)(hp + base);
    if (s > 0)      res = bfmax8(res, *(const uint4*)(hp + base - HD));
    if (s < SD - 1) res = bfmax8(res, *(const uint4*)(hp + base + HD));
    int tile = (s >> 7) * 8 + (j >> 6);
    int slot = frag_slot(s & 127, j & 63);
    *(uint4*)(hF + ((size_t)tile << 13) + slot * 8) = res;
}

// natural-output pool for the final step (head consumes hbuf)
__global__ void maxpool_kernel(const bf16* __restrict__ hp, bf16* __restrict__ hout)
{
    int base = (blockIdx.x * 256 + threadIdx.x) * 8;
    int s = base >> 9;
    uint4 res = *(const uint4*)(hp + base);
    if (s > 0)      res = bfmax8(res, *(const uint4*)(hp + base - HD));
    if (s < SD - 1) res = bfmax8(res, *(const uint4*)(hp + base + HD));
    *(uint4*)(hout + base) = res;
}

// ---------------------------------------------------------------------------
// Generic NT GEMM (m97 structure), 128x128 tile: embed + head.
// ---------------------------------------------------------------------------
constexpr int MODE_BF16 = 0;
constexpr int MODE_SCATTER = 2;   // row r=(s*64+t) -> t*4096+s (natural time-major)

template <int MODE>
__global__ __launch_bounds__(256, 2)
void gemm_kernel(const bf16* __restrict__ A1, int lda1,
                 const bf16* __restrict__ B, int ldb,
                 const float* __restrict__ bias,
                 const float* __restrict__ scale,
                 int relu, void* __restrict__ Cp, int ldc,
                 int K, int ncols)
{
    __shared__ __align__(16) bf16 As[128 * 64];
    __shared__ __align__(16) bf16 Bs[128 * 64];

    const int tid = threadIdx.x;
    const int lane = tid & 63;
    const int w = tid >> 6;
    const int wm = w & 1, wn = w >> 1;
    const int m0 = blockIdx.x * 128, n0 = blockIdx.y * 128;
    const int lm = lane & 15, lq = lane >> 4;

    f4vec acc[4][4];
#pragma unroll
    for (int i = 0; i < 4; ++i)
#pragma unroll
        for (int jj = 0; jj < 4; ++jj) acc[i][jj] = (f4vec){0.f, 0.f, 0.f, 0.f};

    for (int kc = 0; kc < K; kc += 64) {
#pragma unroll
        for (int it = 0; it < 4; ++it) {
            int flat = it * 256 + tid;
            int row = flat >> 3, colu = flat & 7;
            const bf16* ga = A1 + (size_t)(m0 + row) * lda1 + kc + colu * 8;
            const bf16* gb = B + (size_t)(n0 + row) * ldb + kc + colu * 8;
            uint32_t off = (uint32_t)(it * 256 + (tid & ~63)) * 16u;
            async16(ga, (char*)As + off);
            async16(gb, (char*)Bs + off);
        }
        __syncthreads();
#pragma unroll
        for (int ks = 0; ks < 64; ks += 32) {
            s8vec af[4], bfr[4];
#pragma unroll
            for (int mi = 0; mi < 4; ++mi)
                af[mi] = *(const s8vec*)(As + (wm * 64 + mi * 16 + lm) * 64 + ks + lq * 8);
#pragma unroll
            for (int ni = 0; ni < 4; ++ni)
                bfr[ni] = *(const s8vec*)(Bs + (wn * 64 + ni * 16 + lm) * 64 + ks + lq * 8);
#pragma unroll
            for (int mi = 0; mi < 4; ++mi)
#pragma unroll
                for (int ni = 0; ni < 4; ++ni)
                    acc[mi][ni] = __builtin_amdgcn_mfma_f32_16x16x32_bf16(af[mi], bfr[ni], acc[mi][ni], 0, 0, 0);
        }
        __syncthreads();
    }

    const float sc = scale ? scale[0] : 1.0f;
#pragma unroll
    for (int mi = 0; mi < 4; ++mi) {
#pragma unroll
        for (int ni = 0; ni < 4; ++ni) {
            const int gcol = n0 + wn * 64 + ni * 16 + lm;
            const float bv = bias[gcol];
#pragma unroll
            for (int r = 0; r < 4; ++r) {
                const int grow = m0 + wm * 64 + mi * 16 + lq * 4 + r;
                float v = acc[mi][ni][r] * sc + bv;
                if (relu) v = fmaxf(v, 0.f);
                if constexpr (MODE == MODE_BF16) {
                    if (gcol < ncols)
                        ((bf16*)Cp)[(size_t)grow * ldc + gcol] = __float2bfloat16(v);
                } else {
                    const int crow = (grow & 63) * SD + (grow >> 6);
                    ((bf16*)Cp)[(size_t)crow * ldc + gcol] = __float2bfloat16(v);
                }
            }
        }
    }
}

// ---------------------------------------------------------------------------
// Prep: WpackF fragment tiles (gate-permuted) + biasg + weight conversions.
// Tile (nt, ki): row = wq*64+gate*16+lm -> orig = gate*512 + nt*32+wq*16+lm;
// k = ki*64+ks*32+lq*8+e8 (Wih if k<256 else Whh).
// ---------------------------------------------------------------------------
__global__ void prep_kernel(const float* __restrict__ Wih, const float* __restrict__ Whh,
                            const float* __restrict__ bih, const float* __restrict__ bhh,
                            const float* __restrict__ We1, const float* __restrict__ We2,
                            const float* __restrict__ Wout, const float* __restrict__ Wf1,
                            const float* __restrict__ Wf2, const float* __restrict__ bf2,
                            bf16* __restrict__ WpackF, float* __restrict__ biasg,
                            bf16* __restrict__ We1b, bf16* __restrict__ We2b,
                            bf16* __restrict__ Woutb, bf16* __restrict__ Wf1b,
                            bf16* __restrict__ Wf2p, float* __restrict__ bf2f)
{
    int idx = blockIdx.x * 256 + threadIdx.x;
    const int S0 = GD * (ED + HD);
    if (idx < S0) {
        int tile = idx >> 13;
        int within = idx & 8191;
        int slot = within >> 3, e8 = within & 7;
        int nt = tile / 12, ki = tile - nt * 12;
        int lm = slot & 15, lq = (slot >> 4) & 3;
        int gate = (slot >> 6) & 3, ks = (slot >> 8) & 1, wq = slot >> 9;
        int orig = gate * HD + nt * 32 + wq * 16 + lm;
        int k = ki * 64 + ks * 32 + lq * 8 + e8;
        float v = (k < ED) ? Wih[(size_t)orig * ED + k]
                           : Whh[(size_t)orig * HD + (k - ED)];
        WpackF[idx] = __float2bfloat16(v);
        return;
    }
    idx -= S0;
    if (idx < GD) {
        int p = idx, q = p & 127;
        int jv = (p >> 7) * 32 + ((q >> 6) << 4) + (q & 15);
        int gate = (q >> 4) & 3;
        int orig = gate * HD + jv;
        biasg[p] = bih[orig] + bhh[orig];
        return;
    }
    idx -= GD;
    if (idx < EHD * ID) { We1b[idx] = __float2bfloat16(We1[idx]); return; }
    idx -= EHD * ID;
    if (idx < ED * EHD) { We2b[idx] = __float2bfloat16(We2[idx]); return; }
    idx -= ED * EHD;
    if (idx < OD * HD) { Woutb[idx] = __float2bfloat16(Wout[idx]); return; }
    idx -= OD * HD;
    if (idx < F1D * OD) { Wf1b[idx] = __float2bfloat16(Wf1[idx]); return; }
    idx -= F1D * OD;
    if (idx < 128 * F1D) {
        int nrow = idx >> 8;
        Wf2p[idx] = (nrow < F2D) ? __float2bfloat16(Wf2[idx]) : __float2bfloat16(0.f);
        return;
    }
    idx -= 128 * F1D;
    if (idx < 128) { bf2f[idx] = (idx < F2D) ? bf2[idx] : 0.f; return; }
}

__global__ void cvt_input_kernel(const float* __restrict__ src, bf16* __restrict__ dst)
{
    int i = (blockIdx.x * 256 + threadIdx.x) * 8;
    float4 a = *(const float4*)(src + i);
    float4 b = *(const float4*)(src + i + 4);
    bf16 o[8] = { __float2bfloat16(a.x), __float2bfloat16(a.y),
                  __float2bfloat16(a.z), __float2bfloat16(a.w),
                  __float2bfloat16(b.x), __float2bfloat16(b.y),
                  __float2bfloat16(b.z), __float2bfloat16(b.w) };
    *(uint4*)(dst + i) = *(const uint4*)o;
}

__global__ void lane_kernel(const float* __restrict__ lane, const float* __restrict__ Wlg1,
                            const float* __restrict__ blg1, const float* __restrict__ Wlg2,
                            const float* __restrict__ blg2, float* __restrict__ laneC)
{
    if (threadIdx.x != 0) return;
    const float l = lane[0];
    float acc = blg2[0];
    for (int k = 0; k < 32; ++k)
        acc += fmaxf(l * Wlg1[k] + blg1[k], 0.f) * Wlg2[k];
    float v = 1.f / (1.f + __expf(-acc));
    laneC[0] = v;
    laneC[1] = 1.f / v;
}

__global__ void zero_kernel(float* __restrict__ c0, bf16* __restrict__ hF)
{
    int idx = blockIdx.x * 256 + threadIdx.x;
    if (idx < SD * HD) {
        c0[idx] = 0.f;
        hF[idx] = __float2bfloat16(0.f);
    }
}

__global__ void f3_kernel(const bf16* __restrict__ xf2, const float* __restrict__ Wf3,
                          const float* __restrict__ bf3, const float* __restrict__ laneC,
                          float* __restrict__ out)
{
    int s = blockIdx.x * 256 + threadIdx.x;
    if (s >= SD) return;
    float acc = bf3[0];
#pragma unroll
    for (int k = 0; k < F2D; ++k)
        acc += __bfloat162float(xf2[(size_t)s * F2D + k]) * Wf3[k];
    out[s] = acc * laneC[1];
}

__global__ void finalize_kernel(const bf16* __restrict__ h, const float* __restrict__ c,
                                float* __restrict__ out)
{
    int idx = (blockIdx.x * 256 + threadIdx.x) * 4;
    if (idx >= SD * HD) return;
    uint2 hv4 = *(const uint2*)(h + idx);
    const unsigned short* hu = (const unsigned short*)&hv4;
    float4 hf = { bfbits2f(hu[0]), bfbits2f(hu[1]), bfbits2f(hu[2]), bfbits2f(hu[3]) };
    *(float4*)(out + SD + idx) = hf;
    *(float4*)(out + SD + SD * HD + idx) = *(const float4*)(c + idx);
}

// ---------------------------------------------------------------------------
extern "C" void kernel_launch(void* const* d_in, const int* in_sizes, int n_in,
                              void* d_out, int out_size, void* d_ws, size_t ws_size,
                              hipStream_t stream)
{
    (void)in_sizes; (void)n_in; (void)out_size;
    const float* inputDataF = (const float*)d_in[0];
    const float* lane = (const float*)d_in[1];
    const float* Wlg1 = (const float*)d_in[2];
    const float* blg1 = (const float*)d_in[3];
    const float* Wlg2 = (const float*)d_in[4];
    const float* blg2 = (const float*)d_in[5];
    const float* We1 = (const float*)d_in[6];
    const float* be1 = (const float*)d_in[7];
    const float* We2 = (const float*)d_in[8];
    const float* be2 = (const float*)d_in[9];
    const float* Wih = (const float*)d_in[10];
    const float* bih = (const float*)d_in[11];
    const float* Whh = (const float*)d_in[12];
    const float* bhh = (const float*)d_in[13];
    const float* Wout = (const float*)d_in[14];
    const float* bout = (const float*)d_in[15];
    const float* Wf1 = (const float*)d_in[16];
    const float* bf1 = (const float*)d_in[17];
    const float* Wf2 = (const float*)d_in[18];
    const float* bf2 = (const float*)d_in[19];
    const float* Wf3 = (const float*)d_in[20];
    const float* bf3 = (const float*)d_in[21];
    float* out = (float*)d_out;

    char* wp = (char*)d_ws;
    auto carve = [&](size_t bytes) { char* p = wp; wp += (bytes + 255) & ~(size_t)255; return p; };

    bf16* inb   = (bf16*)carve((size_t)SD * TD * ID * 2);
    float* laneCbuf = (float*)carve(2 * sizeof(float));
    float* cbuf0 = (float*)carve((size_t)SD * HD * 4);
    float* cbuf1 = (float*)carve((size_t)SD * HD * 4);
    bf16* hbuf  = (bf16*)carve((size_t)SD * HD * 2);
    bf16* hpre  = (bf16*)carve((size_t)SD * HD * 2);
    bf16* hF    = (bf16*)carve((size_t)SD * HD * 2);
    bf16* WpackF = (bf16*)carve((size_t)GD * (ED + HD) * 2);
    float* biasg = (float*)carve(GD * 4);
    float* bf2f = (float*)carve(128 * 4);
    bf16* We1b  = (bf16*)carve((size_t)EHD * ID * 2);
    bf16* We2b  = (bf16*)carve((size_t)ED * EHD * 2);
    bf16* Woutb = (bf16*)carve((size_t)OD * HD * 2);
    bf16* Wf1b  = (bf16*)carve((size_t)F1D * OD * 2);
    bf16* Wf2p  = (bf16*)carve((size_t)128 * F1D * 2);
    bf16* out_o = (bf16*)carve((size_t)SD * OD * 2);
    bf16* xf1   = (bf16*)carve((size_t)SD * F1D * 2);
    bf16* xf2   = (bf16*)carve((size_t)SD * F2D * 2);

    const size_t SZ_X1 = (size_t)SD * TD * EHD * 2;
    const size_t SZ_X2 = (size_t)SD * TD * ED * 2;
    const size_t used = (size_t)(wp - (char*)d_ws);
    const size_t remain = (ws_size > used) ? (ws_size - used) : 0;
    const bool persist = remain >= (SZ_X1 + SZ_X2 + 4096);

    bf16* x1 = nullptr; bf16* x2 = nullptr;
    bf16* x1t = nullptr; bf16* x2t = nullptr;
    if (persist) {
        x1 = (bf16*)carve(SZ_X1);
        x2 = (bf16*)carve(SZ_X2);
    } else {
        x1t = (bf16*)carve((size_t)SD * EHD * 2);
        x2t = (bf16*)carve((size_t)SD * ED * 2);
    }

    const int PREP_N = GD * (ED + HD) + GD + EHD * ID + ED * EHD + OD * HD
                     + F1D * OD + 128 * F1D + 128;

    cvt_input_kernel<<<SD * TD * ID / (256 * 8), 256, 0, stream>>>(inputDataF, inb);
    prep_kernel<<<(PREP_N + 255) / 256, 256, 0, stream>>>(
        Wih, Whh, bih, bhh, We1, We2, Wout, Wf1, Wf2, bf2,
        WpackF, biasg, We1b, We2b, Woutb, Wf1b, Wf2p, bf2f);
    lane_kernel<<<1, 64, 0, stream>>>(lane, Wlg1, blg1, Wlg2, blg2, laneCbuf);
    zero_kernel<<<SD * HD / 256, 256, 0, stream>>>(cbuf0, hF);

    if (persist) {
        gemm_kernel<MODE_BF16><<<dim3(SD * TD / 128, 1), 256, 0, stream>>>(
            inb, ID, We1b, ID, be1, laneCbuf, 1, x1, EHD, ID, EHD);
        gemm_kernel<MODE_SCATTER><<<dim3(SD * TD / 128, ED / 128), 256, 0, stream>>>(
            x1, EHD, We2b, EHD, be2, nullptr, 1, x2, ED, EHD, ED);
    }

    // LSTM: 64 steps, 2 dispatches each (gemm + frag-pool)
    for (int t = 0; t < TD; ++t) {
        const float* c_in = (t & 1) ? cbuf1 : cbuf0;
        float* c_out = (t & 1) ? cbuf0 : cbuf1;
        const bf16* xA;
        if (persist) {
            xA = x2 + (size_t)t * SD * ED;
        } else {
            gemm_kernel<MODE_BF16><<<dim3(SD / 128, 1), 256, 0, stream>>>(
                inb + (size_t)t * ID, TD * ID, We1b, ID, be1, laneCbuf, 1,
                x1t, EHD, ID, EHD);
            gemm_kernel<MODE_BF16><<<dim3(SD / 128, ED / 128), 256, 0, stream>>>(
                x1t, EHD, We2b, EHD, be2, nullptr, 1, x2t, ED, EHD, ED);
            xA = x2t;
        }
        lstm_gemm2<<<dim3(SD / 128, GD / 128), 256, 0, stream>>>(
            xA, hF, WpackF, biasg, c_in, c_out, hpre);
        if (t < TD - 1)
            pool_frag_kernel<<<SD * HD / (256 * 8), 256, 0, stream>>>(hpre, hF);
    }
    // final: pool hpre -> natural hbuf for the head; c in cbuf0 (t=63 odd)
    maxpool_kernel<<<SD * HD / (256 * 8), 256, 0, stream>>>(hpre, hbuf);

    // Output head
    gemm_kernel<MODE_BF16><<<dim3(SD / 128, 1), 256, 0, stream>>>(
        hbuf, HD, Woutb, HD, bout, nullptr, 0, out_o, OD, HD, OD);
    gemm_kernel<MODE_BF16><<<dim3(SD / 128, F1D / 128), 256, 0, stream>>>(
        out_o, OD, Wf1b, OD, bf1, nullptr, 1, xf1, F1D, OD, F1D);
    gemm_kernel<MODE_BF16><<<dim3(SD / 128, 1), 256, 0, stream>>>(
        xf1, F1D, Wf2p, F1D, bf2f, nullptr, 1, xf2, F2D, F1D, F2D);
    f3_kernel<<<SD / 256, 256, 0, stream>>>(xf2, Wf3, bf3, laneCbuf, out);
    finalize_kernel<<<SD * HD / (256 * 4), 256, 0, stream>>>(hbuf, cbuf0, out);
}